// Round 1
// baseline (227.462 us; speedup 1.0000x reference)
//
#include <hip/hip_runtime.h>

// Problem geometry (fixed by setup_inputs)
constexpr int N_ = 8, C_ = 8, H_ = 1024, W_ = 1024;

// Tiling
constexpr int TW = 64, TH = 16;           // output tile per block
constexpr int TSX = TW + 4, TSY = TH + 4; // 68 x 20 (blur halo = 2)
constexpr int T2SX = TW + 2, T2SY = TH + 2; // 66 x 18 (sobel halo = 1)
constexpr int THREADS = 256;

// Gaussian kernel: cv2.getGaussianKernel(5, 2), normalized
constexpr float G0 = 0.15246914f;
constexpr float G1 = 0.22184130f;
constexpr float G2 = 0.25137912f;

__device__ __forceinline__ int reflect101(int i, int n) {
    if (i < 0) return -i;
    if (i >= n) return 2 * n - 2 - i;
    return i;
}

// Reduce a per-thread float across the block; thread 0 returns the sum.
__device__ __forceinline__ float block_reduce(float v, float* red4) {
    #pragma unroll
    for (int off = 32; off > 0; off >>= 1) v += __shfl_down(v, off);
    const int lane = threadIdx.x & 63, wid = threadIdx.x >> 6;
    if (lane == 0) red4[wid] = v;
    __syncthreads();
    float s = 0.f;
    if (threadIdx.x == 0) s = red4[0] + red4[1] + red4[2] + red4[3];
    __syncthreads();
    return s;
}

__global__ __launch_bounds__(THREADS)
void k1_blur_sums(const float* __restrict__ outp,
                  const float* __restrict__ refp,
                  const float* __restrict__ msp,
                  float* __restrict__ o2p,       // [N,H,W]
                  double* __restrict__ part_ms,
                  double* __restrict__ part_ref)
{
    __shared__ float tile[TSY * TSX];  // out tile + halo (reflect-101)
    __shared__ float hbuf[TSY * TW];   // horizontal-blur intermediate
    __shared__ float red4[4];

    const int t = threadIdx.x;
    const int tx = blockIdx.x, ty = blockIdx.y, n = blockIdx.z;
    const int x0 = tx * TW, y0 = ty * TH;

    // pixel ownership: thread t -> row = t/16, cols 4*(t%16)..+3 (float4-friendly)
    const int row = t >> 4;
    const int col = (t & 15) << 2;

    float accMs = 0.f, accRef = 0.f;
    float4 cs; cs.x = cs.y = cs.z = cs.w = 0.f;

    for (int c = 0; c < C_; ++c) {
        const float* plane = outp + (size_t)(n * C_ + c) * (H_ * W_);

        // stage out tile (+halo 2) with reflect-101 boundary
        for (int i = t; i < TSY * TSX; i += THREADS) {
            int r = i / TSX, q = i - r * TSX;
            int gy = reflect101(y0 + r - 2, H_);
            int gx = reflect101(x0 + q - 2, W_);
            tile[i] = plane[(size_t)gy * W_ + gx];
        }
        __syncthreads();

        // horizontal 5-tap pass: 20 x 64
        for (int i = t; i < TSY * TW; i += THREADS) {
            int r = i >> 6, q = i & 63;
            const float* rp = &tile[r * TSX + q];
            hbuf[i] = G0 * rp[0] + G1 * rp[1] + G2 * rp[2] + G1 * rp[3] + G0 * rp[4];
        }
        __syncthreads();

        // vertical 5-tap + loss accumulation (4 consecutive pixels/thread)
        float4 h0 = *(const float4*)&hbuf[(row + 0) * TW + col];
        float4 h1 = *(const float4*)&hbuf[(row + 1) * TW + col];
        float4 h2 = *(const float4*)&hbuf[(row + 2) * TW + col];
        float4 h3 = *(const float4*)&hbuf[(row + 3) * TW + col];
        float4 h4 = *(const float4*)&hbuf[(row + 4) * TW + col];
        float4 b;
        b.x = G0 * h0.x + G1 * h1.x + G2 * h2.x + G1 * h3.x + G0 * h4.x;
        b.y = G0 * h0.y + G1 * h1.y + G2 * h2.y + G1 * h3.y + G0 * h4.y;
        b.z = G0 * h0.z + G1 * h1.z + G2 * h2.z + G1 * h3.z + G0 * h4.z;
        b.w = G0 * h0.w + G1 * h1.w + G2 * h2.w + G1 * h3.w + G0 * h4.w;

        const size_t gidx = ((size_t)(n * C_ + c) * H_ + (y0 + row)) * W_ + (x0 + col);
        float4 m4 = *(const float4*)(msp + gidx);
        float4 r4 = *(const float4*)(refp + gidx);

        const float* ctr = &tile[(row + 2) * TSX + (col + 2)];
        float o0 = ctr[0], o1 = ctr[1], o2 = ctr[2], o3 = ctr[3];

        accMs  += fabsf(b.x - m4.x) + fabsf(b.y - m4.y) + fabsf(b.z - m4.z) + fabsf(b.w - m4.w);
        accRef += fabsf(o0 - r4.x) + fabsf(o1 - r4.y) + fabsf(o2 - r4.z) + fabsf(o3 - r4.w);
        cs.x += o0; cs.y += o1; cs.z += o2; cs.w += o3;

        __syncthreads();  // protect tile/hbuf before next channel
    }

    // write out2pan = channel mean (coalesced float4)
    {
        float4 w;
        w.x = cs.x * 0.125f; w.y = cs.y * 0.125f; w.z = cs.z * 0.125f; w.w = cs.w * 0.125f;
        *(float4*)&o2p[((size_t)n * H_ + (y0 + row)) * W_ + (x0 + col)] = w;
    }

    float sMs = block_reduce(accMs, red4);
    float sRef = block_reduce(accRef, red4);
    if (t == 0) {
        const int bid = (n * gridDim.y + ty) * gridDim.x + tx;
        part_ms[bid]  = (double)sMs;
        part_ref[bid] = (double)sRef;
    }
}

__global__ __launch_bounds__(THREADS)
void k2_sobel(const float* __restrict__ pan,
              const float* __restrict__ o2p,
              double* __restrict__ part_pan)
{
    __shared__ float d[T2SY * T2SX];  // pan - out2pan, zero-padded
    __shared__ float red4[4];

    const int t = threadIdx.x;
    const int tx = blockIdx.x, ty = blockIdx.y, n = blockIdx.z;
    const int x0 = tx * TW, y0 = ty * TH;
    const size_t base = (size_t)n * (H_ * W_);

    for (int i = t; i < T2SY * T2SX; i += THREADS) {
        int r = i / T2SX, q = i - r * T2SX;
        int gy = y0 + r - 1, gx = x0 + q - 1;
        float v = 0.f;
        if (gy >= 0 && gy < H_ && gx >= 0 && gx < W_) {
            size_t gi = base + (size_t)gy * W_ + gx;
            v = pan[gi] - o2p[gi];
        }
        d[i] = v;
    }
    __syncthreads();

    const int row = (t >> 4) + 1;
    const int colb = ((t & 15) << 2) + 1;
    float acc = 0.f;
    #pragma unroll
    for (int j = 0; j < 4; ++j) {
        const int q = colb + j;
        const float* c0 = &d[(row - 1) * T2SX + q];
        const float* c1 = &d[(row    ) * T2SX + q];
        const float* c2 = &d[(row + 1) * T2SX + q];
        float gx = (c0[1] - c0[-1]) + 2.f * (c1[1] - c1[-1]) + (c2[1] - c2[-1]);
        float gy = (c2[-1] + 2.f * c2[0] + c2[1]) - (c0[-1] + 2.f * c0[0] + c0[1]);
        acc += fabsf(gx) + fabsf(gy);
    }

    float s = block_reduce(acc, red4);
    if (t == 0) {
        const int bid = (n * gridDim.y + ty) * gridDim.x + tx;
        part_pan[bid] = (double)s;
    }
}

__global__ __launch_bounds__(256)
void k3_final(const double* __restrict__ part_ms,
              const double* __restrict__ part_ref,
              const double* __restrict__ part_pan,
              int nb, float* __restrict__ outv)
{
    __shared__ double sMs[256], sRef[256], sPan[256];
    const int t = threadIdx.x;
    double a = 0.0, b = 0.0, c = 0.0;
    for (int i = t; i < nb; i += 256) {
        a += part_ms[i];
        b += part_ref[i];
        c += part_pan[i];
    }
    sMs[t] = a; sRef[t] = b; sPan[t] = c;
    __syncthreads();
    for (int s = 128; s > 0; s >>= 1) {
        if (t < s) { sMs[t] += sMs[t + s]; sRef[t] += sRef[t + s]; sPan[t] += sPan[t + s]; }
        __syncthreads();
    }
    if (t == 0) {
        const double inv_big = 1.0 / (double)(N_ * C_ * H_ * W_);   // 67108864
        const double inv_pan = 1.0 / (double)(N_ * 1 * H_ * W_);    // 8388608
        double total = sMs[0] * inv_big + sRef[0] * inv_big + sPan[0] * inv_pan;
        outv[0] = (float)total;
    }
}

extern "C" void kernel_launch(void* const* d_in, const int* in_sizes, int n_in,
                              void* d_out, int out_size, void* d_ws, size_t ws_size,
                              hipStream_t stream) {
    const float* refp = (const float*)d_in[0];
    const float* pan  = (const float*)d_in[1];
    const float* msp  = (const float*)d_in[2];
    const float* outp = (const float*)d_in[3];

    const int NB = (W_ / TW) * (H_ / TH) * N_;  // 16*64*8 = 8192

    char* ws = (char*)d_ws;
    float* o2p = (float*)ws;                                   // 32 MB
    size_t o2p_bytes = (size_t)N_ * H_ * W_ * sizeof(float);
    double* part_ms  = (double*)(ws + o2p_bytes);
    double* part_ref = part_ms + NB;
    double* part_pan = part_ref + NB;

    dim3 grid(W_ / TW, H_ / TH, N_);
    k1_blur_sums<<<grid, THREADS, 0, stream>>>(outp, refp, msp, o2p, part_ms, part_ref);
    k2_sobel<<<grid, THREADS, 0, stream>>>(pan, o2p, part_pan);
    k3_final<<<1, 256, 0, stream>>>(part_ms, part_ref, part_pan, NB, (float*)d_out);
}

// Round 2
// 203.574 us; speedup vs baseline: 1.1173x; 1.1173x over previous
//
#include <hip/hip_runtime.h>

// Problem geometry (fixed by setup_inputs)
constexpr int N_ = 8, C_ = 8, H_ = 1024, W_ = 1024;

// k1 tiling: 64x32 output tile, blur halo 2
constexpr int TW = 64, TH = 32;
constexpr int TSY = TH + 4;        // 36 staged rows
constexpr int TSTRIDE = 72;        // tile row stride (floats); interior at col 4
constexpr int THREADS = 256;

// k2 tiling (sobel, halo 1)
constexpr int T2W = 64, T2H = 16;
constexpr int T2SX = T2W + 2, T2SY = T2H + 2;

// Gaussian kernel: cv2.getGaussianKernel(5, 2), normalized
constexpr float G0 = 0.15246914f;
constexpr float G1 = 0.22184130f;
constexpr float G2 = 0.25137912f;

__device__ __forceinline__ int reflect101(int i, int n) {
    if (i < 0) return -i;
    if (i >= n) return 2 * n - 2 - i;
    return i;
}

__device__ __forceinline__ float block_reduce(float v, float* red4) {
    #pragma unroll
    for (int off = 32; off > 0; off >>= 1) v += __shfl_down(v, off);
    const int lane = threadIdx.x & 63, wid = threadIdx.x >> 6;
    if (lane == 0) red4[wid] = v;
    __syncthreads();
    float s = 0.f;
    if (threadIdx.x == 0) s = red4[0] + red4[1] + red4[2] + red4[3];
    __syncthreads();
    return s;
}

__global__ __launch_bounds__(THREADS)
void k1_blur_sums(const float* __restrict__ outp,
                  const float* __restrict__ refp,
                  const float* __restrict__ msp,
                  float* __restrict__ o2p,       // [N,H,W]
                  double* __restrict__ part_ms,
                  double* __restrict__ part_ref)
{
    __shared__ float tile[TSY * TSTRIDE];  // out tile; interior cols 4..67, x-halo at 2,3,68,69
    __shared__ float hbuf[TSY * TW];       // horizontally-blurred rows
    __shared__ float red4[4];

    const int t = threadIdx.x;
    const int tx = blockIdx.x, ty = blockIdx.y, n = blockIdx.z;
    const int x0 = tx * TW, y0 = ty * TH;

    // pixel ownership: thread t -> output rows pr, pr+1; cols col..col+3
    const int pr  = (t >> 4) << 1;   // 0,2,...,30
    const int col = (t & 15) << 2;

    float accMs = 0.f, accRef = 0.f;
    float4 cs0 = {0,0,0,0}, cs1 = {0,0,0,0};

    for (int c = 0; c < C_; ++c) {
        const float* plane = outp + (size_t)(n * C_ + c) * (H_ * W_);

        // ---- stage interior: 36 rows x 16 float4, fully coalesced, shifts only
        #pragma unroll
        for (int kk = 0; kk < 3; ++kk) {
            int i = t + kk * 256;
            if (i < TSY * 16) {
                int r = i >> 4, q4 = (i & 15) << 2;
                int gy = reflect101(y0 + r - 2, H_);
                *(float4*)&tile[r * TSTRIDE + 4 + q4] =
                    *(const float4*)&plane[(size_t)gy * W_ + x0 + q4];
            }
        }
        // ---- stage x-halo: 4 cols x 36 rows = 144 scalars
        if (t < TSY * 4) {
            int r = t >> 2, cdx = t & 3;
            int lc = (cdx < 2) ? (2 + cdx) : (66 + cdx);      // lds cols 2,3,68,69
            int gx = reflect101(x0 + ((cdx < 2) ? cdx - 2 : cdx + 62), W_);
            int gy = reflect101(y0 + r - 2, H_);
            tile[r * TSTRIDE + lc] = plane[(size_t)gy * W_ + gx];
        }
        __syncthreads();

        // ---- horizontal 5-tap pass: 36 rows x 64 cols, 4 outputs/iter
        #pragma unroll
        for (int kk = 0; kk < 3; ++kk) {
            int i = t + kk * 256;
            if (i < TSY * 16) {
                int r = i >> 4, q4 = (i & 15) << 2;
                const float* bp = &tile[r * TSTRIDE + 4 + q4];
                float2 l2 = *(const float2*)(bp - 2);
                float4 m4 = *(const float4*)(bp);
                float2 r2 = *(const float2*)(bp + 4);
                float s0 = l2.x, s1 = l2.y, s2 = m4.x, s3 = m4.y;
                float s4 = m4.z, s5 = m4.w, s6 = r2.x, s7 = r2.y;
                float4 h;
                h.x = G0 * (s0 + s4) + G1 * (s1 + s3) + G2 * s2;
                h.y = G0 * (s1 + s5) + G1 * (s2 + s4) + G2 * s3;
                h.z = G0 * (s2 + s6) + G1 * (s3 + s5) + G2 * s4;
                h.w = G0 * (s3 + s7) + G1 * (s4 + s6) + G2 * s5;
                *(float4*)&hbuf[r * TW + q4] = h;
            }
        }
        __syncthreads();

        // ---- vertical 5-tap + loss accumulation: 2 rows x 4 cols per thread
        float4 h0 = *(float4*)&hbuf[(pr + 0) * TW + col];
        float4 h1 = *(float4*)&hbuf[(pr + 1) * TW + col];
        float4 h2 = *(float4*)&hbuf[(pr + 2) * TW + col];
        float4 h3 = *(float4*)&hbuf[(pr + 3) * TW + col];
        float4 h4 = *(float4*)&hbuf[(pr + 4) * TW + col];
        float4 h5 = *(float4*)&hbuf[(pr + 5) * TW + col];

        float4 b0, b1;
        b0.x = G0*(h0.x+h4.x) + G1*(h1.x+h3.x) + G2*h2.x;
        b0.y = G0*(h0.y+h4.y) + G1*(h1.y+h3.y) + G2*h2.y;
        b0.z = G0*(h0.z+h4.z) + G1*(h1.z+h3.z) + G2*h2.z;
        b0.w = G0*(h0.w+h4.w) + G1*(h1.w+h3.w) + G2*h2.w;
        b1.x = G0*(h1.x+h5.x) + G1*(h2.x+h4.x) + G2*h3.x;
        b1.y = G0*(h1.y+h5.y) + G1*(h2.y+h4.y) + G2*h3.y;
        b1.z = G0*(h1.z+h5.z) + G1*(h2.z+h4.z) + G2*h3.z;
        b1.w = G0*(h1.w+h5.w) + G1*(h2.w+h4.w) + G2*h3.w;

        // raw out centers from LDS (tile row = pr+2 maps to image row y0+pr)
        float4 o0 = *(float4*)&tile[(pr + 2) * TSTRIDE + 4 + col];
        float4 o1 = *(float4*)&tile[(pr + 3) * TSTRIDE + 4 + col];

        const size_t gidx = ((size_t)(n * C_ + c) * H_ + (y0 + pr)) * W_ + (x0 + col);
        float4 m0 = *(const float4*)(msp + gidx);
        float4 m1 = *(const float4*)(msp + gidx + W_);
        float4 r0 = *(const float4*)(refp + gidx);
        float4 r1 = *(const float4*)(refp + gidx + W_);

        accMs += fabsf(b0.x - m0.x) + fabsf(b0.y - m0.y) + fabsf(b0.z - m0.z) + fabsf(b0.w - m0.w)
               + fabsf(b1.x - m1.x) + fabsf(b1.y - m1.y) + fabsf(b1.z - m1.z) + fabsf(b1.w - m1.w);
        accRef += fabsf(o0.x - r0.x) + fabsf(o0.y - r0.y) + fabsf(o0.z - r0.z) + fabsf(o0.w - r0.w)
                + fabsf(o1.x - r1.x) + fabsf(o1.y - r1.y) + fabsf(o1.z - r1.z) + fabsf(o1.w - r1.w);
        cs0.x += o0.x; cs0.y += o0.y; cs0.z += o0.z; cs0.w += o0.w;
        cs1.x += o1.x; cs1.y += o1.y; cs1.z += o1.z; cs1.w += o1.w;

        __syncthreads();  // protect tile/hbuf before next channel
    }

    // write out2pan = channel mean (coalesced float4, 2 rows)
    {
        const size_t oidx = ((size_t)n * H_ + (y0 + pr)) * W_ + (x0 + col);
        float4 w0, w1;
        w0.x = cs0.x * 0.125f; w0.y = cs0.y * 0.125f; w0.z = cs0.z * 0.125f; w0.w = cs0.w * 0.125f;
        w1.x = cs1.x * 0.125f; w1.y = cs1.y * 0.125f; w1.z = cs1.z * 0.125f; w1.w = cs1.w * 0.125f;
        *(float4*)&o2p[oidx] = w0;
        *(float4*)&o2p[oidx + W_] = w1;
    }

    float sMs = block_reduce(accMs, red4);
    float sRef = block_reduce(accRef, red4);
    if (t == 0) {
        const int bid = (n * gridDim.y + ty) * gridDim.x + tx;
        part_ms[bid]  = (double)sMs;
        part_ref[bid] = (double)sRef;
    }
}

__global__ __launch_bounds__(THREADS)
void k2_sobel(const float* __restrict__ pan,
              const float* __restrict__ o2p,
              double* __restrict__ part_pan)
{
    __shared__ float d[T2SY * T2SX];  // pan - out2pan, zero-padded
    __shared__ float red4[4];

    const int t = threadIdx.x;
    const int tx = blockIdx.x, ty = blockIdx.y, n = blockIdx.z;
    const int x0 = tx * T2W, y0 = ty * T2H;
    const size_t base = (size_t)n * (H_ * W_);

    for (int i = t; i < T2SY * T2SX; i += THREADS) {
        int r = i / T2SX, q = i - r * T2SX;
        int gy = y0 + r - 1, gx = x0 + q - 1;
        float v = 0.f;
        if (gy >= 0 && gy < H_ && gx >= 0 && gx < W_) {
            size_t gi = base + (size_t)gy * W_ + gx;
            v = pan[gi] - o2p[gi];
        }
        d[i] = v;
    }
    __syncthreads();

    const int row = (t >> 4) + 1;
    const int colb = ((t & 15) << 2) + 1;
    float acc = 0.f;
    #pragma unroll
    for (int j = 0; j < 4; ++j) {
        const int q = colb + j;
        const float* c0 = &d[(row - 1) * T2SX + q];
        const float* c1 = &d[(row    ) * T2SX + q];
        const float* c2 = &d[(row + 1) * T2SX + q];
        float gx = (c0[1] - c0[-1]) + 2.f * (c1[1] - c1[-1]) + (c2[1] - c2[-1]);
        float gy = (c2[-1] + 2.f * c2[0] + c2[1]) - (c0[-1] + 2.f * c0[0] + c0[1]);
        acc += fabsf(gx) + fabsf(gy);
    }

    float s = block_reduce(acc, red4);
    if (t == 0) {
        const int bid = (n * gridDim.y + ty) * gridDim.x + tx;
        part_pan[bid] = (double)s;
    }
}

__global__ __launch_bounds__(256)
void k3_final(const double* __restrict__ part_ms,
              const double* __restrict__ part_ref,
              const double* __restrict__ part_pan,
              int nb1, int nb2, float* __restrict__ outv)
{
    __shared__ double sMs[256], sRef[256], sPan[256];
    const int t = threadIdx.x;
    double a = 0.0, b = 0.0, c = 0.0;
    for (int i = t; i < nb1; i += 256) {
        a += part_ms[i];
        b += part_ref[i];
    }
    for (int i = t; i < nb2; i += 256) {
        c += part_pan[i];
    }
    sMs[t] = a; sRef[t] = b; sPan[t] = c;
    __syncthreads();
    for (int s = 128; s > 0; s >>= 1) {
        if (t < s) { sMs[t] += sMs[t + s]; sRef[t] += sRef[t + s]; sPan[t] += sPan[t + s]; }
        __syncthreads();
    }
    if (t == 0) {
        const double inv_big = 1.0 / (double)(N_ * C_ * H_ * W_);   // 67108864
        const double inv_pan = 1.0 / (double)(N_ * 1 * H_ * W_);    // 8388608
        double total = sMs[0] * inv_big + sRef[0] * inv_big + sPan[0] * inv_pan;
        outv[0] = (float)total;
    }
}

extern "C" void kernel_launch(void* const* d_in, const int* in_sizes, int n_in,
                              void* d_out, int out_size, void* d_ws, size_t ws_size,
                              hipStream_t stream) {
    const float* refp = (const float*)d_in[0];
    const float* pan  = (const float*)d_in[1];
    const float* msp  = (const float*)d_in[2];
    const float* outp = (const float*)d_in[3];

    const int NB1 = (W_ / TW) * (H_ / TH) * N_;    // 16*32*8 = 4096 (k1)
    const int NB2 = (W_ / T2W) * (H_ / T2H) * N_;  // 16*64*8 = 8192 (k2)

    char* ws = (char*)d_ws;
    float* o2p = (float*)ws;                                   // 32 MB
    size_t o2p_bytes = (size_t)N_ * H_ * W_ * sizeof(float);
    double* part_ms  = (double*)(ws + o2p_bytes);
    double* part_ref = part_ms + NB1;
    double* part_pan = part_ref + NB1;

    dim3 grid1(W_ / TW, H_ / TH, N_);
    k1_blur_sums<<<grid1, THREADS, 0, stream>>>(outp, refp, msp, o2p, part_ms, part_ref);
    dim3 grid2(W_ / T2W, H_ / T2H, N_);
    k2_sobel<<<grid2, THREADS, 0, stream>>>(pan, o2p, part_pan);
    k3_final<<<1, 256, 0, stream>>>(part_ms, part_ref, part_pan, NB1, NB2, (float*)d_out);
}